// Round 2
// baseline (281.664 us; speedup 1.0000x reference)
//
#include <hip/hip_runtime.h>
#include <cstdint>
#include <cstddef>

#define B_ 4
#define T_ 2048
#define D_ 1024
#define H_ 16

typedef __attribute__((ext_vector_type(8))) short short8;     // 8 bf16 (4 VGPRs) for MFMA A/B frags
typedef __attribute__((ext_vector_type(4))) float f32x4;      // MFMA C/D frag
typedef __attribute__((ext_vector_type(8))) unsigned short u16x8;

__device__ __forceinline__ unsigned short f2b16(float f) {
  union { float f; unsigned int u; } un; un.f = f;
  unsigned int r = un.u + 0x7fffu + ((un.u >> 16) & 1u);  // round-to-nearest-even
  return (unsigned short)(r >> 16);
}
__device__ __forceinline__ void async_cp16(const void* g, void* l) {
  __builtin_amdgcn_global_load_lds((const __attribute__((address_space(1))) void*)g,
                                   (__attribute__((address_space(3))) void*)l,
                                   16, 0, 0);
}

// ---------------- LayerNorm: fp32 in -> bf16 normalized out -------------
__global__ __launch_bounds__(256) void ln_kernel(const float* __restrict__ x,
                                                 const float* __restrict__ gamma,
                                                 const float* __restrict__ beta,
                                                 unsigned short* __restrict__ xn) {
  const int row = blockIdx.x;
  const int t = threadIdx.x;
  const float4 v = ((const float4*)(x + (size_t)row * D_))[t];
  float s  = v.x + v.y + v.z + v.w;
  float s2 = v.x*v.x + v.y*v.y + v.z*v.z + v.w*v.w;
  #pragma unroll
  for (int off = 32; off > 0; off >>= 1) {
    s  += __shfl_down(s, off);
    s2 += __shfl_down(s2, off);
  }
  __shared__ float sh[8];
  const int wv = t >> 6, lane = t & 63;
  if (lane == 0) { sh[wv] = s; sh[4 + wv] = s2; }
  __syncthreads();
  if (t == 0) {
    float ts  = sh[0] + sh[1] + sh[2] + sh[3];
    float ts2 = sh[4] + sh[5] + sh[6] + sh[7];
    float mu  = ts * (1.0f / D_);
    float var = ts2 * (1.0f / D_) - mu * mu;
    sh[0] = mu;
    sh[1] = rsqrtf(var + 1e-5f);
  }
  __syncthreads();
  const float mu = sh[0], rs = sh[1];
  const float4 g  = ((const float4*)gamma)[t];
  const float4 bb = ((const float4*)beta)[t];
  ushort4 o;
  o.x = f2b16((v.x - mu) * rs * g.x + bb.x);
  o.y = f2b16((v.y - mu) * rs * g.y + bb.y);
  o.z = f2b16((v.z - mu) * rs * g.z + bb.z);
  o.w = f2b16((v.w - mu) * rs * g.w + bb.w);
  ((ushort4*)(xn + (size_t)row * D_))[t] = o;
}

// ---------- transpose + cast: w[K][N] fp32 -> wT[N][K] bf16 -------------
__global__ __launch_bounds__(256) void transpose_cast(const float* __restrict__ w,
                                                      unsigned short* __restrict__ wT,
                                                      int K, int N) {
  __shared__ float tile[32][33];
  const int n0 = blockIdx.x * 32;
  const int k0 = blockIdx.y * 32;
  const int tx = threadIdx.x, ty = threadIdx.y;
  #pragma unroll
  for (int i = 0; i < 32; i += 8)
    tile[ty + i][tx] = w[(size_t)(k0 + ty + i) * N + n0 + tx];
  __syncthreads();
  #pragma unroll
  for (int i = 0; i < 32; i += 8)
    wT[(size_t)(n0 + ty + i) * K + k0 + tx] = f2b16(tile[tx][ty + i]);
}

// ---- transpose V: vB[bh][t][dv] -> vtB[bh][dv][t'] (c' permuted) -------
// c'(t) chosen so attention's PV A-fragment packing is lane-LOCAL after the
// swapped (S^T) QK^T:  kv' = ks*32 + quad*8 + j  <->  kv = (2ks+(j>>2))*16
// + quad*4 + (j&3).  As a bit-permutation of c = kv':
//   t = {b5, b2, b4, b3, b1, b0}  (bit positions 32,16,8,4,2,1)
__global__ __launch_bounds__(256) void transpose_v(const unsigned short* __restrict__ vB,
                                                   unsigned short* __restrict__ vtB) {
  __shared__ unsigned short tile[64 * 66];
  const int tid = threadIdx.x;
  const int bh = blockIdx.x;
  const int t0 = blockIdx.y * 64;
  const int lr = tid >> 2, lc = (tid & 3) * 16;
  const unsigned short* src = vB + ((size_t)bh * T_ + t0) * 64;
  *(u16x8*)&tile[lr * 66 + lc]     = *(const u16x8*)(src + (size_t)lr * 64 + lc);
  *(u16x8*)&tile[lr * 66 + lc + 8] = *(const u16x8*)(src + (size_t)lr * 64 + lc + 8);
  __syncthreads();
  const int dv = tid >> 2, cb = (tid & 3) * 16;
  unsigned short outv[16];
  #pragma unroll
  for (int j = 0; j < 16; ++j) {
    const int c = cb + j;
    const int t = (c & 32) | ((c & 4) << 2) | ((c & 16) >> 1) | ((c & 8) >> 1) | (c & 3);
    outv[j] = tile[t * 66 + dv];
  }
  unsigned short* dst = vtB + ((size_t)bh * 64 + dv) * T_ + t0 + cb;
  *(u16x8*)dst       = *(const u16x8*)&outv[0];
  *(u16x8*)(dst + 8) = *(const u16x8*)&outv[8];
}

// ============ 256x256 8-phase QKV GEMM (T2+T3+T4+T5 template) ===========
// BM=BN=256, BK=64, 512 threads = 8 waves (WARPS_M=4 x WARPS_N=2), per-wave
// output 128(rows, 2 qm-halves of 32) x 64(cols... per wave: rows =
// qm*128 + wr*32, cols = qn*128 + wc*64; quadrant (qm,qn) = 32x64 = 16 MFMA.
// LDS 128KB: A,B tiles as 2 halves of [128][64] bf16, double-buffered,
// chunk-XOR swizzled (chunk' = c ^ (row&7)) -> conflict-free ds_read_b128.
// Schedule per K-tile: 4 phases, each {ds_read frags || issue 1 half-tile
// of tile kt+1 -> lgkmcnt(0)+sched_barrier -> setprio(1) 16 MFMA} with
// COUNTED vmcnt fences (4/4/-/4, never 0 mid-loop) before raw s_barrier.
// Half-tile issue order per tile: Ah0,Bh0,Bh1,Ah1; fence at end of phase
// p forces exactly the half-tile phase p+1 reads (FIFO vmcnt semantics).
// Epilogue: per-quadrant per-wave LDS restage (dead A-buf) -> coalesced
// 1KB b128 row stores into split qB(scaled)/kB/vB.
__global__ __launch_bounds__(512, 2) void gemm256_qkv(const unsigned short* __restrict__ A,
                                                      const unsigned short* __restrict__ Bt,
                                                      const float* __restrict__ bias,
                                                      unsigned short* __restrict__ qB,
                                                      unsigned short* __restrict__ kB,
                                                      unsigned short* __restrict__ vB) {
  constexpr int K = 1024;
  constexpr int NT = K / 64;            // 16 K-tiles
  __shared__ __align__(16) unsigned short As[32768];   // 64KB: [buf][half][128][64]
  __shared__ __align__(16) unsigned short Bs[32768];   // 64KB

  const int tid  = threadIdx.x;
  const int lane = tid & 63;
  const int wv   = tid >> 6;            // 0..7
  const int l15  = lane & 15, quad = lane >> 4;
  const int wr   = wv >> 1;             // 0..3  (32-row slice within each qm-half)
  const int wc   = wv & 1;              // 0..1  (64-col slice within each qn-half)

  // XCD-bijective swizzle: 384 blocks, 48 tiles per XCD chunk (384%8==0)
  const int w = (blockIdx.x & 7) * 48 + (blockIdx.x >> 3);
  const int tileM = (w & 31) * 256;     // 32 M-tiles
  const int tileN = (w >> 5) * 256;     // 12 N-tiles

  // ---- staging geometry: half-tile = [128][64], 2 issues x 512thr x 16B
  const int sr  = tid >> 3;                       // 0..63 (row within issue-set)
  const int scs = ((tid & 7) ^ (sr & 7)) * 8;     // pre-swizzled global chunk (shorts)
  const unsigned short* gA = A  + (size_t)(tileM + sr) * K + scs;
  const unsigned short* gB = Bt + (size_t)(tileN + sr) * K + scs;

  auto stageA = [&](int h, int ko, int wbuf) {
    const unsigned short* g = gA + (size_t)(h * 128) * K + ko;
    unsigned short* l = &As[wbuf * 16384 + h * 8192 + tid * 8];
    async_cp16(g, l);
    async_cp16(g + (size_t)64 * K, l + 4096);
  };
  auto stageB = [&](int h, int ko, int wbuf) {
    const unsigned short* g = gB + (size_t)(h * 128) * K + ko;
    unsigned short* l = &Bs[wbuf * 16384 + h * 8192 + tid * 8];
    async_cp16(g, l);
    async_cp16(g + (size_t)64 * K, l + 4096);
  };

  // ---- fragment-read geometry (row&7 == l15&7 for all frag rows)
  const int rA  = wr * 32 + l15;                  // A half-local row (fm adds 16)
  const int rB  = wc * 64 + l15;                  // B half-local row (fn adds 16)
  const int ck0 = ((0 + quad) ^ (l15 & 7)) * 8;   // k-chunk, ks=0 (swizzled, shorts)
  const int ck1 = ((4 + quad) ^ (l15 & 7)) * 8;   // ks=1

  f32x4 acc[2][2][2][4] = {};                     // [qm][qn][fm][fn]

#define MFMA16(QM, QN, AF, BF)                                                          \
  do {                                                                                  \
    _Pragma("unroll") for (int fm = 0; fm < 2; ++fm)                                    \
    _Pragma("unroll") for (int fn = 0; fn < 4; ++fn) {                                  \
      acc[QM][QN][fm][fn] = __builtin_amdgcn_mfma_f32_16x16x32_bf16(                    \
          AF[fm][0], BF[fn][0], acc[QM][QN][fm][fn], 0, 0, 0);                          \
      acc[QM][QN][fm][fn] = __builtin_amdgcn_mfma_f32_16x16x32_bf16(                    \
          AF[fm][1], BF[fn][1], acc[QM][QN][fm][fn], 0, 0, 0);                          \
    }                                                                                   \
  } while (0)

  // ---- prologue: stage tile 0 (order Ah0,Bh0,Bh1,Ah1), force Ah0+Bh0
  stageA(0, 0, 0);
  stageB(0, 0, 0);
  stageB(1, 0, 0);
  stageA(1, 0, 0);
  asm volatile("s_waitcnt vmcnt(4)" ::: "memory");
  asm volatile("s_barrier" ::: "memory");

  #pragma unroll 2
  for (int kt = 0; kt < NT; ++kt) {
    const int buf = kt & 1;
    const unsigned short* Ab = &As[buf * 16384];
    const unsigned short* Bb = &Bs[buf * 16384];
    const int wbuf = buf ^ 1;
    const bool st = (kt + 1) < NT;
    const int ko = (kt + 1) * 64;

    short8 a[2][2], b0[4][2], b1[4][2];

    // ---- phase 0: quadrant (0,0); reads A-half0 + B-half0 (12 ds_reads)
    #pragma unroll
    for (int fm = 0; fm < 2; ++fm) {
      a[fm][0] = *(const short8*)&Ab[(rA + fm * 16) * 64 + ck0];
      a[fm][1] = *(const short8*)&Ab[(rA + fm * 16) * 64 + ck1];
    }
    #pragma unroll
    for (int fn = 0; fn < 4; ++fn) {
      b0[fn][0] = *(const short8*)&Bb[(rB + fn * 16) * 64 + ck0];
      b0[fn][1] = *(const short8*)&Bb[(rB + fn * 16) * 64 + ck1];
    }
    if (st) stageA(0, ko, wbuf);
    asm volatile("s_waitcnt lgkmcnt(0)" ::: "memory");
    __builtin_amdgcn_sched_barrier(0);
    __builtin_amdgcn_s_setprio(1);
    MFMA16(0, 0, a, b0);
    __builtin_amdgcn_s_setprio(0);
    if (st) asm volatile("s_waitcnt vmcnt(4)" ::: "memory");   // force Bh1(kt)
    else    asm volatile("s_waitcnt vmcnt(2)" ::: "memory");
    asm volatile("s_barrier" ::: "memory");

    // ---- phase 1: quadrant (0,1); reads B-half1 (8 ds_reads)
    #pragma unroll
    for (int fn = 0; fn < 4; ++fn) {
      b1[fn][0] = *(const short8*)&Bb[8192 + (rB + fn * 16) * 64 + ck0];
      b1[fn][1] = *(const short8*)&Bb[8192 + (rB + fn * 16) * 64 + ck1];
    }
    if (st) stageB(0, ko, wbuf);
    asm volatile("s_waitcnt lgkmcnt(0)" ::: "memory");
    __builtin_amdgcn_sched_barrier(0);
    __builtin_amdgcn_s_setprio(1);
    MFMA16(0, 1, a, b1);
    __builtin_amdgcn_s_setprio(0);
    if (st) asm volatile("s_waitcnt vmcnt(4)" ::: "memory");   // force Ah1(kt)
    else    asm volatile("s_waitcnt vmcnt(0)" ::: "memory");
    asm volatile("s_barrier" ::: "memory");

    // ---- phase 2: quadrant (1,0); reads A-half1 (4 ds_reads; b0 reused)
    #pragma unroll
    for (int fm = 0; fm < 2; ++fm) {
      a[fm][0] = *(const short8*)&Ab[8192 + (rA + fm * 16) * 64 + ck0];
      a[fm][1] = *(const short8*)&Ab[8192 + (rA + fm * 16) * 64 + ck1];
    }
    if (st) stageB(1, ko, wbuf);
    asm volatile("s_waitcnt lgkmcnt(0)" ::: "memory");
    __builtin_amdgcn_sched_barrier(0);
    __builtin_amdgcn_s_setprio(1);
    MFMA16(1, 0, a, b0);
    __builtin_amdgcn_s_setprio(0);
    asm volatile("s_barrier" ::: "memory");                    // no fence needed

    // ---- phase 3: quadrant (1,1); no ds_reads (a,b1 reused)
    if (st) stageA(1, ko, wbuf);
    __builtin_amdgcn_s_setprio(1);
    MFMA16(1, 1, a, b1);
    __builtin_amdgcn_s_setprio(0);
    if (st) asm volatile("s_waitcnt vmcnt(4)" ::: "memory");   // force Ah0+Bh0(kt+1)
    asm volatile("s_barrier" ::: "memory");
  }
#undef MFMA16

  // ---- epilogue: per-wave scratch in dead LDS (all DMA drained by tail fences)
  unsigned short* E = &As[wv * 2304];   // 32 rows x 72 (stride 72: conflict-free b128)
  #pragma unroll
  for (int qm = 0; qm < 2; ++qm) {
    #pragma unroll
    for (int qn = 0; qn < 2; ++qn) {
      const int colBase = tileN + qn * 128 + wc * 64;    // 64-aligned head slice
      const int rowBase = tileM + qm * 128 + wr * 32;
      #pragma unroll
      for (int fn = 0; fn < 4; ++fn) {
        const int col = colBase + fn * 16 + l15;
        const float bv = bias[col];
        const float sc = (col < 1024) ? 0.180336880f : 1.0f;  // Q: fold 0.125*log2e
        #pragma unroll
        for (int fm = 0; fm < 2; ++fm)
          #pragma unroll
          for (int r = 0; r < 4; ++r)
            E[(fm * 16 + quad * 4 + r) * 72 + fn * 16 + l15] =
                f2b16((acc[qm][qn][fm][fn][r] + bv) * sc);
      }
      const int secq = colBase >> 10;                    // 0=Q, 1=K, 2=V
      const int hh   = (colBase & 1023) >> 6;
      unsigned short* outSec = (secq == 0) ? qB : (secq == 1) ? kB : vB;
      #pragma unroll
      for (int it = 0; it < 4; ++it) {
        const int lrow = it * 8 + (lane >> 3);
        const int row = rowBase + lrow;
        const int b_ = row >> 11, t = row & 2047;
        const u16x8 val = *(const u16x8*)&E[lrow * 72 + (lane & 7) * 8];
        *(u16x8*)(outSec + ((size_t)(b_ * 16 + hh) * T_ + t) * 64 + (lane & 7) * 8) = val;
      }
    }
  }
}

// ------------- MFMA GEMM (m97 structure) — MODE 1 only now --------------
// out fp32 = acc + bias + residual (output projection).
template <int MODE>
__global__ __launch_bounds__(256) void gemm_bt(const unsigned short* __restrict__ A,
                                               const unsigned short* __restrict__ Bt,
                                               const float* __restrict__ bias,
                                               const float* __restrict__ resid,
                                               float* __restrict__ outF,
                                               int M, int N, int K) {
  __shared__ unsigned short As[128 * 32];
  __shared__ unsigned short Bs[128 * 32];
  const int tid  = threadIdx.x;
  const int lane = tid & 63;
  const int wv   = tid >> 6;
  const int wm   = (wv & 1) * 64;
  const int wn   = (wv >> 1) * 64;
  const int tileM = blockIdx.x * 128;
  const int tileN = blockIdx.y * 128;
  const int l15 = lane & 15, quad = lane >> 4;
  const int sRow = tid >> 2;
  const int sCol = (tid & 3) * 8;

  f32x4 acc[4][4] = {};

  const unsigned short* aG0 = A  + (size_t)(tileM + sRow) * K + sCol;
  const unsigned short* aG1 = A  + (size_t)(tileM + 64 + sRow) * K + sCol;
  const unsigned short* bG0 = Bt + (size_t)(tileN + sRow) * K + sCol;
  const unsigned short* bG1 = Bt + (size_t)(tileN + 64 + sRow) * K + sCol;
  unsigned short* lA0 = &As[tid * 8];
  unsigned short* lA1 = &As[2048 + tid * 8];
  unsigned short* lB0 = &Bs[tid * 8];
  unsigned short* lB1 = &Bs[2048 + tid * 8];

  for (int k0 = 0; k0 < K; k0 += 32) {
    async_cp16(aG0 + k0, lA0);
    async_cp16(aG1 + k0, lA1);
    async_cp16(bG0 + k0, lB0);
    async_cp16(bG1 + k0, lB1);
    __syncthreads();

    short8 a[4], b[4];
    #pragma unroll
    for (int i = 0; i < 4; ++i) {
      a[i] = *(const short8*)&As[(wm + i * 16 + l15) * 32 + quad * 8];
      b[i] = *(const short8*)&Bs[(wn + i * 16 + l15) * 32 + quad * 8];
    }
    #pragma unroll
    for (int mi = 0; mi < 4; ++mi)
      #pragma unroll
      for (int ni = 0; ni < 4; ++ni)
        acc[mi][ni] = __builtin_amdgcn_mfma_f32_16x16x32_bf16(a[mi], b[ni], acc[mi][ni], 0, 0, 0);
    __syncthreads();
  }

  // epilogue: C/D layout col=lane&15, row=quad*4+r (m89/m91-verified)
  #pragma unroll
  for (int ni = 0; ni < 4; ++ni) {
    const int col = tileN + wn + ni * 16 + l15;
    const float bv = bias[col];
    #pragma unroll
    for (int mi = 0; mi < 4; ++mi) {
      #pragma unroll
      for (int r = 0; r < 4; ++r) {
        const int row = tileM + wm + mi * 16 + quad * 4 + r;
        const size_t idx = (size_t)row * N + col;
        outF[idx] = acc[mi][ni][r] + bv + resid[idx];
      }
    }
  }
}

// ---------------- MFMA flash attention v8 ------------------------------
// 4 waves x 32 q-rows, grid 1024, 32KB LDS -> 4 blocks/CU (one residency
// wave, no tail). Swapped QK^T (S^T) -> P repack fully in-register.
__global__ __launch_bounds__(256, 4) void attn_mfma(const unsigned short* __restrict__ qB,
                                                    const unsigned short* __restrict__ kB,
                                                    const unsigned short* __restrict__ vtB,
                                                    unsigned short* __restrict__ aout) {
  __shared__ unsigned short Ks[2][64 * 64];   // swizzled K tiles [kv][hd]
  __shared__ unsigned short Vs[2][64 * 64];   // swizzled V^T tiles [dv][c']

  const int tid = threadIdx.x;
  const int bid = blockIdx.x;
  const int bh = bid & 63;            // all 16 q-blocks of a bh on one XCD
  const int qb = bid >> 6;
  const int b = bh >> 4, h = bh & 15;
  const int wv = tid >> 6, lane = tid & 63;
  const int l15 = lane & 15, quad = lane >> 4;

  const unsigned short* qP = qB  + (size_t)bh * T_ * 64;
  const unsigned short* kP = kB  + (size_t)bh * T_ * 64;
  const unsigned short* vP = vtB + (size_t)bh * 64 * T_;
  const int q0 = qb * 128 + wv * 32;

  // resident Q fragments (B-operand): [n=q=l15][k=quad*8+j]
  short8 qf[2][2];
  #pragma unroll
  for (int mi = 0; mi < 2; ++mi)
    #pragma unroll
    for (int ks = 0; ks < 2; ++ks)
      qf[mi][ks] = *(const short8*)(qP + ((size_t)(q0 + mi * 16 + l15)) * 64 + ks * 32 + quad * 8);

  const short8 onesf = {0x3F80, 0x3F80, 0x3F80, 0x3F80, 0x3F80, 0x3F80, 0x3F80, 0x3F80};
  f32x4 accO[2][5] = {};

  const int lrow  = lane >> 3;
  const int lchnk = (lane & 7) ^ (lrow & 7);
  const size_t kOff0 = (size_t)((wv * 2 + 0) * 8 + lrow) * 64 + lchnk * 8;
  const size_t kOff1 = (size_t)((wv * 2 + 1) * 8 + lrow) * 64 + lchnk * 8;
  const size_t vOff0 = (size_t)((wv * 2 + 0) * 8 + lrow) * T_ + lchnk * 8;
  const size_t vOff1 = (size_t)((wv * 2 + 1) * 8 + lrow) * T_ + lchnk * 8;
  const int lOff0 = (wv * 2 + 0) * 512 + lane * 8;
  const int lOff1 = (wv * 2 + 1) * 512 + lane * 8;

  // stage tile 0
  async_cp16(kP + kOff0, &Ks[0][lOff0]);
  async_cp16(kP + kOff1, &Ks[0][lOff1]);
  async_cp16(vP + vOff0, &Vs[0][lOff0]);
  async_cp16(vP + vOff1, &Vs[0][lOff1]);
  __syncthreads();   // drains vmcnt(0): tile 0 visible

  for (int kt = 0; kt < 32; ++kt) {
    const int buf = kt & 1;
    if (kt + 1 < 32) {
      const unsigned short* kg = kP + (size_t)(kt + 1) * 64 * 64;
      const unsigned short* vg = vP + (kt + 1) * 64;
      async_cp16(kg + kOff0, &Ks[buf ^ 1][lOff0]);
      async_cp16(kg + kOff1, &Ks[buf ^ 1][lOff1]);
      async_cp16(vg + vOff0, &Vs[buf ^ 1][lOff0]);
      async_cp16(vg + vOff1, &Vs[buf ^ 1][lOff1]);
    }
    const unsigned short* K_ = Ks[buf];
    const unsigned short* V_ = Vs[buf];

    // S^T = K @ Q^T : lane holds S[q = mi*16 + l15][kv = cc*16 + quad*4 + r]
    f32x4 accT[4][2] = {};
    #pragma unroll
    for (int ks = 0; ks < 2; ++ks) {
      #pragma unroll
      for (int cc = 0; cc < 4; ++cc) {
        const short8 kb = *(const short8*)&K_[(cc * 16 + l15) * 64 +
                                              (((ks << 2) | quad) ^ (l15 & 7)) * 8];
        accT[cc][0] = __builtin_amdgcn_mfma_f32_16x16x32_bf16(kb, qf[0][ks], accT[cc][0], 0, 0, 0);
        accT[cc][1] = __builtin_amdgcn_mfma_f32_16x16x32_bf16(kb, qf[1][ks], accT[cc][1], 0, 0, 0);
      }
    }

    // P repack fully in-register
    short8 pa[2][2];
    #pragma unroll
    for (int mi = 0; mi < 2; ++mi) {
      #pragma unroll
      for (int ks = 0; ks < 2; ++ks) {
        union { unsigned short u[8]; short8 s; } pk;
        #pragma unroll
        for (int r = 0; r < 4; ++r) {
          union { float f; unsigned int u; } e0, e1;
          e0.f = __builtin_amdgcn_exp2f(accT[2 * ks + 0][mi][r]);
          e1.f = __builtin_amdgcn_exp2f(accT[2 * ks + 1][mi][r]);
          pk.u[r]     = (unsigned short)(e0.u >> 16);
          pk.u[4 + r] = (unsigned short)(e1.u >> 16);
        }
        pa[mi][ks] = pk.s;
      }
    }

    // O += P @ V' ; nj=4 = ones (l sum)
    #pragma unroll
    for (int ks = 0; ks < 2; ++ks) {
      short8 vb[4];
      #pragma unroll
      for (int nj = 0; nj < 4; ++nj)
        vb[nj] = *(const short8*)&V_[(nj * 16 + l15) * 64 +
                                     (((ks << 2) | quad) ^ (l15 & 7)) * 8];
      #pragma unroll
      for (int mi = 0; mi < 2; ++mi) {
        #pragma unroll
        for (int nj = 0; nj < 4; ++nj)
          accO[mi][nj] = __builtin_amdgcn_mfma_f32_16x16x32_bf16(pa[mi][ks], vb[nj], accO[mi][nj], 0, 0, 0);
        accO[mi][4] = __builtin_amdgcn_mfma_f32_16x16x32_bf16(pa[mi][ks], onesf, accO[mi][4], 0, 0, 0);
      }
    }

    __syncthreads();  // single barrier: drains next-tile DMA + guards buffers
  }

  // normalize by l and store bf16
  #pragma unroll
  for (int mi = 0; mi < 2; ++mi) {
    #pragma unroll
    for (int r = 0; r < 4; ++r) {
      const float inv = 1.0f / accO[mi][4][r];
      const int row = q0 + mi * 16 + quad * 4 + r;
      unsigned short* op = aout + (size_t)(b * T_ + row) * D_ + h * 64 + l15;
      #pragma unroll
      for (int nj = 0; nj < 4; ++nj)
        op[nj * 16] = f2b16(accO[mi][nj][r] * inv);
    }
  }
}

extern "C" void kernel_launch(void* const* d_in, const int* in_sizes, int n_in,
                              void* d_out, int out_size, void* d_ws, size_t ws_size,
                              hipStream_t stream) {
  const float* x      = (const float*)d_in[0];
  const float* w_qkv  = (const float*)d_in[1];
  const float* b_qkv  = (const float*)d_in[2];
  const float* w_proj = (const float*)d_in[3];
  const float* b_proj = (const float*)d_in[4];
  const float* ln_g   = (const float*)d_in[5];
  const float* ln_b   = (const float*)d_in[6];
  float* out = (float*)d_out;

  char* ws = (char*)d_ws;
  unsigned short* xn   = (unsigned short*)(ws);                       // 16 MB (reused as aout)
  unsigned short* wTq  = (unsigned short*)(ws + (size_t)(16 << 20));  //  6 MB
  unsigned short* wTp  = (unsigned short*)(ws + (size_t)(22 << 20));  //  2 MB
  unsigned short* qBuf = (unsigned short*)(ws + (size_t)(24 << 20));  // 16 MB
  unsigned short* kBuf = (unsigned short*)(ws + (size_t)(40 << 20));  // 16 MB
  unsigned short* vBuf = (unsigned short*)(ws + (size_t)(56 << 20));  // 16 MB
  unsigned short* vtB  = (unsigned short*)(ws + (size_t)(72 << 20));  // 16 MB
  unsigned short* aout = xn;   // xn is dead after QKV gemm; attn reuses it

  // 1. LayerNorm -> bf16
  ln_kernel<<<8192, 256, 0, stream>>>(x, ln_g, ln_b, xn);
  // 2. weights -> transposed bf16 (Bt layout)
  transpose_cast<<<dim3(96, 32), dim3(32, 8), 0, stream>>>(w_qkv, wTq, 1024, 3072);
  transpose_cast<<<dim3(32, 32), dim3(32, 8), 0, stream>>>(w_proj, wTp, 1024, 1024);
  // 3. QKV projection: 256^2 8-phase template, 384 blocks (32M x 12N)
  gemm256_qkv<<<384, 512, 0, stream>>>(xn, wTq, b_qkv, qBuf, kBuf, vBuf);
  // 3b. V -> V^T with c' permutation
  transpose_v<<<dim3(64, 32), 256, 0, stream>>>(vBuf, vtB);
  // 4. MFMA flash attention v8
  attn_mfma<<<1024, 256, 0, stream>>>(qBuf, kBuf, vtB, aout);
  // 5. output projection + bias + residual, fp32 out
  gemm_bt<1><<<dim3(64, 8), 256, 0, stream>>>(aout, wTp, b_proj, x, out, 8192, 1024, 1024);
}

// Round 3
// 270.201 us; speedup vs baseline: 1.0424x; 1.0424x over previous
//
#include <hip/hip_runtime.h>
#include <cstdint>
#include <cstddef>

#define B_ 4
#define T_ 2048
#define D_ 1024
#define H_ 16

typedef __attribute__((ext_vector_type(8))) short short8;     // 8 bf16 (4 VGPRs) for MFMA A/B frags
typedef __attribute__((ext_vector_type(4))) float f32x4;      // MFMA C/D frag
typedef __attribute__((ext_vector_type(8))) unsigned short u16x8;

__device__ __forceinline__ unsigned short f2b16(float f) {
  union { float f; unsigned int u; } un; un.f = f;
  unsigned int r = un.u + 0x7fffu + ((un.u >> 16) & 1u);  // round-to-nearest-even
  return (unsigned short)(r >> 16);
}
__device__ __forceinline__ void async_cp16(const void* g, void* l) {
  __builtin_amdgcn_global_load_lds((const __attribute__((address_space(1))) void*)g,
                                   (__attribute__((address_space(3))) void*)l,
                                   16, 0, 0);
}
__device__ __forceinline__ f32x4 mfma16(short8 a, short8 b, f32x4 c) {
  return __builtin_amdgcn_mfma_f32_16x16x32_bf16(a, b, c, 0, 0, 0);
}

// ---------------- LayerNorm: fp32 in -> bf16 normalized out -------------
__global__ __launch_bounds__(256) void ln_kernel(const float* __restrict__ x,
                                                 const float* __restrict__ gamma,
                                                 const float* __restrict__ beta,
                                                 unsigned short* __restrict__ xn) {
  const int row = blockIdx.x;
  const int t = threadIdx.x;
  const float4 v = ((const float4*)(x + (size_t)row * D_))[t];
  float s  = v.x + v.y + v.z + v.w;
  float s2 = v.x*v.x + v.y*v.y + v.z*v.z + v.w*v.w;
  #pragma unroll
  for (int off = 32; off > 0; off >>= 1) {
    s  += __shfl_down(s, off);
    s2 += __shfl_down(s2, off);
  }
  __shared__ float sh[8];
  const int wv = t >> 6, lane = t & 63;
  if (lane == 0) { sh[wv] = s; sh[4 + wv] = s2; }
  __syncthreads();
  if (t == 0) {
    float ts  = sh[0] + sh[1] + sh[2] + sh[3];
    float ts2 = sh[4] + sh[5] + sh[6] + sh[7];
    float mu  = ts * (1.0f / D_);
    float var = ts2 * (1.0f / D_) - mu * mu;
    sh[0] = mu;
    sh[1] = rsqrtf(var + 1e-5f);
  }
  __syncthreads();
  const float mu = sh[0], rs = sh[1];
  const float4 g  = ((const float4*)gamma)[t];
  const float4 bb = ((const float4*)beta)[t];
  ushort4 o;
  o.x = f2b16((v.x - mu) * rs * g.x + bb.x);
  o.y = f2b16((v.y - mu) * rs * g.y + bb.y);
  o.z = f2b16((v.z - mu) * rs * g.z + bb.z);
  o.w = f2b16((v.w - mu) * rs * g.w + bb.w);
  ((ushort4*)(xn + (size_t)row * D_))[t] = o;
}

// ---------- transpose + cast: w[K][N] fp32 -> wT[N][K] bf16 -------------
__global__ __launch_bounds__(256) void transpose_cast(const float* __restrict__ w,
                                                      unsigned short* __restrict__ wT,
                                                      int K, int N) {
  __shared__ float tile[32][33];
  const int n0 = blockIdx.x * 32;
  const int k0 = blockIdx.y * 32;
  const int tx = threadIdx.x, ty = threadIdx.y;
  #pragma unroll
  for (int i = 0; i < 32; i += 8)
    tile[ty + i][tx] = w[(size_t)(k0 + ty + i) * N + n0 + tx];
  __syncthreads();
  #pragma unroll
  for (int i = 0; i < 32; i += 8)
    wT[(size_t)(n0 + ty + i) * K + k0 + tx] = f2b16(tile[tx][ty + i]);
}

// ---- transpose V: vB[bh][t][dv] -> vtB[bh][dv][t'] (c' permuted) -------
// c'(t) chosen so attention's PV A-fragment packing is lane-LOCAL after the
// swapped (S^T) QK^T:  t = {b5, b2, b4, b3, b1, b0}
__global__ __launch_bounds__(256) void transpose_v(const unsigned short* __restrict__ vB,
                                                   unsigned short* __restrict__ vtB) {
  __shared__ unsigned short tile[64 * 66];
  const int tid = threadIdx.x;
  const int bh = blockIdx.x;
  const int t0 = blockIdx.y * 64;
  const int lr = tid >> 2, lc = (tid & 3) * 16;
  const unsigned short* src = vB + ((size_t)bh * T_ + t0) * 64;
  *(u16x8*)&tile[lr * 66 + lc]     = *(const u16x8*)(src + (size_t)lr * 64 + lc);
  *(u16x8*)&tile[lr * 66 + lc + 8] = *(const u16x8*)(src + (size_t)lr * 64 + lc + 8);
  __syncthreads();
  const int dv = tid >> 2, cb = (tid & 3) * 16;
  unsigned short outv[16];
  #pragma unroll
  for (int j = 0; j < 16; ++j) {
    const int c = cb + j;
    const int t = (c & 32) | ((c & 4) << 2) | ((c & 16) >> 1) | ((c & 8) >> 1) | (c & 3);
    outv[j] = tile[t * 66 + dv];
  }
  unsigned short* dst = vtB + ((size_t)bh * 64 + dv) * T_ + t0 + cb;
  *(u16x8*)dst       = *(const u16x8*)&outv[0];
  *(u16x8*)(dst + 8) = *(const u16x8*)&outv[8];
}

// ========== 128x256 8-phase GEMM template (balanced grid) ===============
// BM=128, BN=256, BK=64, 512 thr = 8 waves (4M x 2N): wave = 32 rows
// (wr*16 per qm-half) x 128 cols (wc*64 per qn-half). Phases iterate
// quadrants (qm: A-half of 64 rows, qn: B-half of 128 rows) so EVERY wave
// reads the same half in the same phase (fence-schedule uniformity).
// LDS 96KB (A 2x8KB halves, B 2x16KB halves, double-buffered, chunk-XOR
// swizzled) -> 1 block/CU, grid 768 = 3 perfectly-balanced rounds (MODE 0)
// or 256 = 1 round (MODE 1). Per-thread FIFO staging: 6 cps/tile in order
// [Ah0, Bh0 x2, Bh1 x2, Ah1]; counted fences end-ph0 vmcnt(2), end-ph1
// vmcnt(3), end-ph3 vmcnt(3) (never 0 mid-loop); drain 1/0 on last tile.
// MODE 0: split bf16 epilogue -> qB (scaled), kB, vB via per-wave LDS
// restage (64-col head slices). MODE 1: fp32 = acc + bias + resid.
template <int MODE, int NN>
__global__ __launch_bounds__(512, 2) void gemm8p(const unsigned short* __restrict__ A,
                                                 const unsigned short* __restrict__ Bt,
                                                 const float* __restrict__ bias,
                                                 const float* __restrict__ resid,
                                                 unsigned short* __restrict__ qB,
                                                 unsigned short* __restrict__ kB,
                                                 unsigned short* __restrict__ vB,
                                                 float* __restrict__ outF) {
  constexpr int K = 1024;
  constexpr int NT = 16;                               // K / 64
  __shared__ __align__(16) unsigned short As[16384];   // 32KB [buf][qm-half][64][64]
  __shared__ __align__(16) unsigned short Bs[32768];   // 64KB [buf][qn-half][128][64]

  const int tid  = threadIdx.x;
  const int lane = tid & 63;
  const int wv   = tid >> 6;            // 0..7
  const int l15  = lane & 15, quad = lane >> 4;
  const int wr   = wv >> 1;             // 0..3: 16-row slice in each qm-half
  const int wc   = wv & 1;              // 0..1: 64-col slice in each qn-half

  // XCD-bijective swizzle: grid = 64 * (NN/256) tiles, % 8 == 0
  constexpr int CPX = (64 * (NN / 256)) / 8;
  const int w = (blockIdx.x & 7) * CPX + (blockIdx.x >> 3);
  const int tileM = (w & 63) * 128;
  const int tileN = (w >> 6) * 256;

  // staging: issue-set = 64 rows x 128B; thread -> row tid>>3, chunk tid&7,
  // pre-swizzled global chunk (c ^ row&7) -> LDS linear = swizzled layout
  const int sr  = tid >> 3;
  const int scs = ((tid & 7) ^ (sr & 7)) * 8;
  const unsigned short* gA = A  + (size_t)(tileM + sr) * K + scs;
  const unsigned short* gB = Bt + (size_t)(tileN + sr) * K + scs;

  auto stA = [&](int h, int ko, int wb) {   // A half h = 64 rows, 1 cp
    async_cp16(gA + (size_t)(h * 64) * K + ko, &As[wb * 8192 + h * 4096 + tid * 8]);
  };
  auto stB = [&](int h, int ko, int wb) {   // B half h = 128 rows, 2 cps
    const unsigned short* g = gB + (size_t)(h * 128) * K + ko;
    unsigned short* l = &Bs[wb * 16384 + h * 8192 + tid * 8];
    async_cp16(g, l);
    async_cp16(g + (size_t)64 * K, l + 4096);
  };

  // fragment geometry (row&7 == l15&7 for all frag rows -> swizzle consistent)
  const int rA  = wr * 16 + l15;                  // A half-local row
  const int rB  = wc * 64 + l15;                  // B half-local row (fn adds 16)
  const int ck0 = ((0 + quad) ^ (l15 & 7)) * 8;   // swizzled k-chunk, ks=0
  const int ck1 = ((4 + quad) ^ (l15 & 7)) * 8;   // ks=1

  f32x4 acc[2][2][4] = {};                        // [qm][qn][fn]

  // prologue: tile 0 in FIFO order; force Ah0+Bh0 (retire 3), keep 3 in flight
  stA(0, 0, 0); stB(0, 0, 0); stB(1, 0, 0); stA(1, 0, 0);
  asm volatile("s_waitcnt vmcnt(3)" ::: "memory");
  asm volatile("s_barrier" ::: "memory");

  #pragma unroll 2
  for (int kt = 0; kt < NT; ++kt) {
    const int buf = kt & 1;
    const unsigned short* Ab = &As[buf * 8192];
    const unsigned short* Bb = &Bs[buf * 16384];
    const int wb = buf ^ 1;
    const bool st = (kt + 1) < NT;
    const int ko = (kt + 1) * 64;

    short8 a[2], b0[4][2], b1[4][2];

    // ---- phase 0: (qm0, qn0); reads Ah0 + Bh0 (10 ds_reads)
    a[0] = *(const short8*)&Ab[rA * 64 + ck0];
    a[1] = *(const short8*)&Ab[rA * 64 + ck1];
    #pragma unroll
    for (int fn = 0; fn < 4; ++fn) {
      b0[fn][0] = *(const short8*)&Bb[(rB + fn * 16) * 64 + ck0];
      b0[fn][1] = *(const short8*)&Bb[(rB + fn * 16) * 64 + ck1];
    }
    if (st) stA(0, ko, wb);
    asm volatile("s_waitcnt lgkmcnt(0)" ::: "memory");
    __builtin_amdgcn_sched_barrier(0);
    __builtin_amdgcn_s_setprio(1);
    #pragma unroll
    for (int fn = 0; fn < 4; ++fn) {
      acc[0][0][fn] = mfma16(a[0], b0[fn][0], acc[0][0][fn]);
      acc[0][0][fn] = mfma16(a[1], b0[fn][1], acc[0][0][fn]);
    }
    __builtin_amdgcn_s_setprio(0);
    if (st) asm volatile("s_waitcnt vmcnt(2)" ::: "memory");   // retire Bh1(kt)
    else    asm volatile("s_waitcnt vmcnt(1)" ::: "memory");
    asm volatile("s_barrier" ::: "memory");

    // ---- phase 1: (qm0, qn1); reads Bh1 (8 ds_reads)
    #pragma unroll
    for (int fn = 0; fn < 4; ++fn) {
      b1[fn][0] = *(const short8*)&Bb[8192 + (rB + fn * 16) * 64 + ck0];
      b1[fn][1] = *(const short8*)&Bb[8192 + (rB + fn * 16) * 64 + ck1];
    }
    if (st) stB(0, ko, wb);
    asm volatile("s_waitcnt lgkmcnt(0)" ::: "memory");
    __builtin_amdgcn_sched_barrier(0);
    __builtin_amdgcn_s_setprio(1);
    #pragma unroll
    for (int fn = 0; fn < 4; ++fn) {
      acc[0][1][fn] = mfma16(a[0], b1[fn][0], acc[0][1][fn]);
      acc[0][1][fn] = mfma16(a[1], b1[fn][1], acc[0][1][fn]);
    }
    __builtin_amdgcn_s_setprio(0);
    if (st) asm volatile("s_waitcnt vmcnt(3)" ::: "memory");   // retire Ah1(kt)
    else    asm volatile("s_waitcnt vmcnt(0)" ::: "memory");
    asm volatile("s_barrier" ::: "memory");

    // ---- phase 2: (qm1, qn0); reads Ah1 (2 ds_reads; b0 reused)
    a[0] = *(const short8*)&Ab[4096 + rA * 64 + ck0];
    a[1] = *(const short8*)&Ab[4096 + rA * 64 + ck1];
    if (st) stB(1, ko, wb);
    asm volatile("s_waitcnt lgkmcnt(0)" ::: "memory");
    __builtin_amdgcn_sched_barrier(0);
    __builtin_amdgcn_s_setprio(1);
    #pragma unroll
    for (int fn = 0; fn < 4; ++fn) {
      acc[1][0][fn] = mfma16(a[0], b0[fn][0], acc[1][0][fn]);
      acc[1][0][fn] = mfma16(a[1], b0[fn][1], acc[1][0][fn]);
    }
    __builtin_amdgcn_s_setprio(0);
    asm volatile("s_barrier" ::: "memory");                    // no fence needed

    // ---- phase 3: (qm1, qn1); no ds_reads (a, b1 reused)
    if (st) stA(1, ko, wb);
    __builtin_amdgcn_s_setprio(1);
    #pragma unroll
    for (int fn = 0; fn < 4; ++fn) {
      acc[1][1][fn] = mfma16(a[0], b1[fn][0], acc[1][1][fn]);
      acc[1][1][fn] = mfma16(a[1], b1[fn][1], acc[1][1][fn]);
    }
    __builtin_amdgcn_s_setprio(0);
    if (st) asm volatile("s_waitcnt vmcnt(3)" ::: "memory");   // retire Ah0+Bh0(kt+1)
    asm volatile("s_barrier" ::: "memory");
  }

  // ---- epilogue (all DMA drained; final barrier passed: LDS reusable)
  if constexpr (MODE == 0) {
    unsigned short* E = &As[wv * 1152];   // per-wave 16 x 72 scratch
    #pragma unroll
    for (int qm = 0; qm < 2; ++qm) {
      #pragma unroll
      for (int qn = 0; qn < 2; ++qn) {
        const int colBase = tileN + qn * 128 + wc * 64;   // 64-aligned head slice
        const int rowBase = tileM + qm * 64 + wr * 16;
        #pragma unroll
        for (int fn = 0; fn < 4; ++fn) {
          const int col = colBase + fn * 16 + l15;
          const float bv = bias[col];
          const float sc = (col < 1024) ? 0.180336880f : 1.0f;  // Q: 0.125*log2e
          #pragma unroll
          for (int r = 0; r < 4; ++r)
            E[(quad * 4 + r) * 72 + fn * 16 + l15] =
                f2b16((acc[qm][qn][fn][r] + bv) * sc);
        }
        const int secq = colBase >> 10;                   // 0=Q, 1=K, 2=V
        const int hh   = (colBase & 1023) >> 6;
        unsigned short* outSec = (secq == 0) ? qB : (secq == 1) ? kB : vB;
        #pragma unroll
        for (int it = 0; it < 2; ++it) {
          const int lrow = it * 8 + (lane >> 3);
          const int row = rowBase + lrow;
          const int b_ = row >> 11, t = row & 2047;
          const u16x8 val = *(const u16x8*)&E[lrow * 72 + (lane & 7) * 8];
          *(u16x8*)(outSec + ((size_t)(b_ * 16 + hh) * T_ + t) * 64 + (lane & 7) * 8) = val;
        }
      }
    }
  } else {
    #pragma unroll
    for (int qm = 0; qm < 2; ++qm) {
      #pragma unroll
      for (int qn = 0; qn < 2; ++qn) {
        #pragma unroll
        for (int fn = 0; fn < 4; ++fn) {
          const int col = tileN + qn * 128 + wc * 64 + fn * 16 + l15;
          const float bv = bias[col];
          #pragma unroll
          for (int r = 0; r < 4; ++r) {
            const int row = tileM + qm * 64 + wr * 16 + quad * 4 + r;
            const size_t idx = (size_t)row * NN + col;
            outF[idx] = acc[qm][qn][fn][r] + bv + resid[idx];
          }
        }
      }
    }
  }
}

// ---------------- MFMA flash attention v8 ------------------------------
// 4 waves x 32 q-rows, grid 1024, 32KB LDS -> 4 blocks/CU (one residency
// wave, no tail). Swapped QK^T (S^T) -> P repack fully in-register.
__global__ __launch_bounds__(256, 4) void attn_mfma(const unsigned short* __restrict__ qB,
                                                    const unsigned short* __restrict__ kB,
                                                    const unsigned short* __restrict__ vtB,
                                                    unsigned short* __restrict__ aout) {
  __shared__ unsigned short Ks[2][64 * 64];   // swizzled K tiles [kv][hd]
  __shared__ unsigned short Vs[2][64 * 64];   // swizzled V^T tiles [dv][c']

  const int tid = threadIdx.x;
  const int bid = blockIdx.x;
  const int bh = bid & 63;            // all 16 q-blocks of a bh on one XCD
  const int qb = bid >> 6;
  const int b = bh >> 4, h = bh & 15;
  const int wv = tid >> 6, lane = tid & 63;
  const int l15 = lane & 15, quad = lane >> 4;

  const unsigned short* qP = qB  + (size_t)bh * T_ * 64;
  const unsigned short* kP = kB  + (size_t)bh * T_ * 64;
  const unsigned short* vP = vtB + (size_t)bh * 64 * T_;
  const int q0 = qb * 128 + wv * 32;

  // resident Q fragments (B-operand): [n=q=l15][k=quad*8+j]
  short8 qf[2][2];
  #pragma unroll
  for (int mi = 0; mi < 2; ++mi)
    #pragma unroll
    for (int ks = 0; ks < 2; ++ks)
      qf[mi][ks] = *(const short8*)(qP + ((size_t)(q0 + mi * 16 + l15)) * 64 + ks * 32 + quad * 8);

  const short8 onesf = {0x3F80, 0x3F80, 0x3F80, 0x3F80, 0x3F80, 0x3F80, 0x3F80, 0x3F80};
  f32x4 accO[2][5] = {};

  const int lrow  = lane >> 3;
  const int lchnk = (lane & 7) ^ (lrow & 7);
  const size_t kOff0 = (size_t)((wv * 2 + 0) * 8 + lrow) * 64 + lchnk * 8;
  const size_t kOff1 = (size_t)((wv * 2 + 1) * 8 + lrow) * 64 + lchnk * 8;
  const size_t vOff0 = (size_t)((wv * 2 + 0) * 8 + lrow) * T_ + lchnk * 8;
  const size_t vOff1 = (size_t)((wv * 2 + 1) * 8 + lrow) * T_ + lchnk * 8;
  const int lOff0 = (wv * 2 + 0) * 512 + lane * 8;
  const int lOff1 = (wv * 2 + 1) * 512 + lane * 8;

  // stage tile 0
  async_cp16(kP + kOff0, &Ks[0][lOff0]);
  async_cp16(kP + kOff1, &Ks[0][lOff1]);
  async_cp16(vP + vOff0, &Vs[0][lOff0]);
  async_cp16(vP + vOff1, &Vs[0][lOff1]);
  __syncthreads();   // drains vmcnt(0): tile 0 visible

  for (int kt = 0; kt < 32; ++kt) {
    const int buf = kt & 1;
    if (kt + 1 < 32) {
      const unsigned short* kg = kP + (size_t)(kt + 1) * 64 * 64;
      const unsigned short* vg = vP + (kt + 1) * 64;
      async_cp16(kg + kOff0, &Ks[buf ^ 1][lOff0]);
      async_cp16(kg + kOff1, &Ks[buf ^ 1][lOff1]);
      async_cp16(vg + vOff0, &Vs[buf ^ 1][lOff0]);
      async_cp16(vg + vOff1, &Vs[buf ^ 1][lOff1]);
    }
    const unsigned short* K_ = Ks[buf];
    const unsigned short* V_ = Vs[buf];

    // S^T = K @ Q^T : lane holds S[q = mi*16 + l15][kv = cc*16 + quad*4 + r]
    f32x4 accT[4][2] = {};
    #pragma unroll
    for (int ks = 0; ks < 2; ++ks) {
      #pragma unroll
      for (int cc = 0; cc < 4; ++cc) {
        const short8 kb = *(const short8*)&K_[(cc * 16 + l15) * 64 +
                                              (((ks << 2) | quad) ^ (l15 & 7)) * 8];
        accT[cc][0] = mfma16(kb, qf[0][ks], accT[cc][0]);
        accT[cc][1] = mfma16(kb, qf[1][ks], accT[cc][1]);
      }
    }

    // P repack fully in-register
    short8 pa[2][2];
    #pragma unroll
    for (int mi = 0; mi < 2; ++mi) {
      #pragma unroll
      for (int ks = 0; ks < 2; ++ks) {
        union { unsigned short u[8]; short8 s; } pk;
        #pragma unroll
        for (int r = 0; r < 4; ++r) {
          union { float f; unsigned int u; } e0, e1;
          e0.f = __builtin_amdgcn_exp2f(accT[2 * ks + 0][mi][r]);
          e1.f = __builtin_amdgcn_exp2f(accT[2 * ks + 1][mi][r]);
          pk.u[r]     = (unsigned short)(e0.u >> 16);
          pk.u[4 + r] = (unsigned short)(e1.u >> 16);
        }
        pa[mi][ks] = pk.s;
      }
    }

    // O += P @ V' ; nj=4 = ones (l sum)
    #pragma unroll
    for (int ks = 0; ks < 2; ++ks) {
      short8 vb[4];
      #pragma unroll
      for (int nj = 0; nj < 4; ++nj)
        vb[nj] = *(const short8*)&V_[(nj * 16 + l15) * 64 +
                                     (((ks << 2) | quad) ^ (l15 & 7)) * 8];
      #pragma unroll
      for (int mi = 0; mi < 2; ++mi) {
        #pragma unroll
        for (int nj = 0; nj < 4; ++nj)
          accO[mi][nj] = mfma16(pa[mi][ks], vb[nj], accO[mi][nj]);
        accO[mi][4] = mfma16(pa[mi][ks], onesf, accO[mi][4]);
      }
    }

    __syncthreads();  // single barrier: drains next-tile DMA + guards buffers
  }

  // normalize by l and store bf16
  #pragma unroll
  for (int mi = 0; mi < 2; ++mi) {
    #pragma unroll
    for (int r = 0; r < 4; ++r) {
      const float inv = 1.0f / accO[mi][4][r];
      const int row = q0 + mi * 16 + quad * 4 + r;
      unsigned short* op = aout + (size_t)(b * T_ + row) * D_ + h * 64 + l15;
      #pragma unroll
      for (int nj = 0; nj < 4; ++nj)
        op[nj * 16] = f2b16(accO[mi][nj][r] * inv);
    }
  }
}

extern "C" void kernel_launch(void* const* d_in, const int* in_sizes, int n_in,
                              void* d_out, int out_size, void* d_ws, size_t ws_size,
                              hipStream_t stream) {
  const float* x      = (const float*)d_in[0];
  const float* w_qkv  = (const float*)d_in[1];
  const float* b_qkv  = (const float*)d_in[2];
  const float* w_proj = (const float*)d_in[3];
  const float* b_proj = (const float*)d_in[4];
  const float* ln_g   = (const float*)d_in[5];
  const float* ln_b   = (const float*)d_in[6];
  float* out = (float*)d_out;

  char* ws = (char*)d_ws;
  unsigned short* xn   = (unsigned short*)(ws);                       // 16 MB (reused as aout)
  unsigned short* wTq  = (unsigned short*)(ws + (size_t)(16 << 20));  //  6 MB
  unsigned short* wTp  = (unsigned short*)(ws + (size_t)(22 << 20));  //  2 MB
  unsigned short* qBuf = (unsigned short*)(ws + (size_t)(24 << 20));  // 16 MB
  unsigned short* kBuf = (unsigned short*)(ws + (size_t)(40 << 20));  // 16 MB
  unsigned short* vBuf = (unsigned short*)(ws + (size_t)(56 << 20));  // 16 MB
  unsigned short* vtB  = (unsigned short*)(ws + (size_t)(72 << 20));  // 16 MB
  unsigned short* aout = xn;   // xn is dead after QKV gemm; attn reuses it

  // 1. LayerNorm -> bf16
  ln_kernel<<<8192, 256, 0, stream>>>(x, ln_g, ln_b, xn);
  // 2. weights -> transposed bf16 (Bt layout)
  transpose_cast<<<dim3(96, 32), dim3(32, 8), 0, stream>>>(w_qkv, wTq, 1024, 3072);
  transpose_cast<<<dim3(32, 32), dim3(32, 8), 0, stream>>>(w_proj, wTp, 1024, 1024);
  // 3. QKV projection: 128x256 8-phase, 768 blocks = 3 balanced rounds
  gemm8p<0, 3072><<<768, 512, 0, stream>>>(xn, wTq, b_qkv, nullptr,
                                           qBuf, kBuf, vBuf, nullptr);
  // 3b. V -> V^T with c' permutation
  transpose_v<<<dim3(64, 32), 256, 0, stream>>>(vBuf, vtB);
  // 4. MFMA flash attention v8
  attn_mfma<<<1024, 256, 0, stream>>>(qBuf, kBuf, vtB, aout);
  // 5. output projection: same template, 256 blocks = 1 round, fp32 + resid
  gemm8p<1, 1024><<<256, 512, 0, stream>>>(aout, wTp, b_proj, x,
                                           nullptr, nullptr, nullptr, out);
}

// Round 4
// 268.571 us; speedup vs baseline: 1.0487x; 1.0061x over previous
//
#include <hip/hip_runtime.h>
#include <cstdint>
#include <cstddef>

#define B_ 4
#define T_ 2048
#define D_ 1024
#define H_ 16

typedef __attribute__((ext_vector_type(8))) short short8;     // 8 bf16 (4 VGPRs) for MFMA A/B frags
typedef __attribute__((ext_vector_type(4))) float f32x4;      // MFMA C/D frag
typedef __attribute__((ext_vector_type(8))) unsigned short u16x8;

__device__ __forceinline__ unsigned short f2b16(float f) {
  union { float f; unsigned int u; } un; un.f = f;
  unsigned int r = un.u + 0x7fffu + ((un.u >> 16) & 1u);  // round-to-nearest-even
  return (unsigned short)(r >> 16);
}
__device__ __forceinline__ void async_cp16(const void* g, void* l) {
  __builtin_amdgcn_global_load_lds((const __attribute__((address_space(1))) void*)g,
                                   (__attribute__((address_space(3))) void*)l,
                                   16, 0, 0);
}
__device__ __forceinline__ f32x4 mfma16(short8 a, short8 b, f32x4 c) {
  return __builtin_amdgcn_mfma_f32_16x16x32_bf16(a, b, c, 0, 0, 0);
}

// ====== prep: fused LayerNorm + transpose_cast(w_qkv) + transpose_cast(w_proj)
// One dispatch replaces three (launch-gap ~10us each). Blocks:
//   [0, 8192)        : LN row  (fp32 -> bf16 normalized)
//   [8192, 11264)    : w_qkv transpose 96x32 tiles
//   [11264, 12288)   : w_proj transpose 32x32 tiles
__global__ __launch_bounds__(256) void prep_kernel(const float* __restrict__ x,
                                                   const float* __restrict__ gamma,
                                                   const float* __restrict__ beta,
                                                   unsigned short* __restrict__ xn,
                                                   const float* __restrict__ wq,
                                                   unsigned short* __restrict__ wTq,
                                                   const float* __restrict__ wp,
                                                   unsigned short* __restrict__ wTp) {
  __shared__ float sh[8];
  __shared__ float tile[32][33];
  const int bid = blockIdx.x;
  const int t = threadIdx.x;

  if (bid < 8192) {
    // ---- LayerNorm ----
    const int row = bid;
    const float4 v = ((const float4*)(x + (size_t)row * D_))[t];
    float s  = v.x + v.y + v.z + v.w;
    float s2 = v.x*v.x + v.y*v.y + v.z*v.z + v.w*v.w;
    #pragma unroll
    for (int off = 32; off > 0; off >>= 1) {
      s  += __shfl_down(s, off);
      s2 += __shfl_down(s2, off);
    }
    const int wv = t >> 6, lane = t & 63;
    if (lane == 0) { sh[wv] = s; sh[4 + wv] = s2; }
    __syncthreads();
    if (t == 0) {
      float ts  = sh[0] + sh[1] + sh[2] + sh[3];
      float ts2 = sh[4] + sh[5] + sh[6] + sh[7];
      float mu  = ts * (1.0f / D_);
      float var = ts2 * (1.0f / D_) - mu * mu;
      sh[0] = mu;
      sh[1] = rsqrtf(var + 1e-5f);
    }
    __syncthreads();
    const float mu = sh[0], rs = sh[1];
    const float4 g  = ((const float4*)gamma)[t];
    const float4 bb = ((const float4*)beta)[t];
    ushort4 o;
    o.x = f2b16((v.x - mu) * rs * g.x + bb.x);
    o.y = f2b16((v.y - mu) * rs * g.y + bb.y);
    o.z = f2b16((v.z - mu) * rs * g.z + bb.z);
    o.w = f2b16((v.w - mu) * rs * g.w + bb.w);
    ((ushort4*)(xn + (size_t)row * D_))[t] = o;
  } else {
    // ---- transpose + cast ----
    const float* w; unsigned short* wT; int K, N, bx, by;
    if (bid < 8192 + 3072) {
      const int idx = bid - 8192;
      w = wq; wT = wTq; K = 1024; N = 3072; bx = idx % 96; by = idx / 96;
    } else {
      const int idx = bid - 11264;
      w = wp; wT = wTp; K = 1024; N = 1024; bx = idx % 32; by = idx / 32;
    }
    const int n0 = bx * 32, k0 = by * 32;
    const int tx = t & 31, ty = t >> 5;
    #pragma unroll
    for (int i = 0; i < 32; i += 8)
      tile[ty + i][tx] = w[(size_t)(k0 + ty + i) * N + n0 + tx];
    __syncthreads();
    #pragma unroll
    for (int i = 0; i < 32; i += 8)
      wT[(size_t)(n0 + ty + i) * K + k0 + tx] = f2b16(tile[tx][ty + i]);
  }
}

// ============ 256x256 8-phase QKV GEMM (proven R1/R2 schedule) ==========
// BM=BN=256, BK=64, 512 threads = 8 waves (4M x 2N). Per-phase 16 MFMA,
// counted vmcnt fences (4/4/-/4), 1 barrier/phase. Grid 384 (32M x 12N).
// Epilogue: Q/K blocks (tileN < 2048): per-wave LDS restage -> coalesced
// b128 stores into qB (scaled) / kB. V blocks (tileN >= 2048): V^T fused —
// cross-wave LDS transpose tiles [64 dv][68] (in dead As/Bs), c' column
// permutation (inverse of attn's t(c) map) applied at write, coalesced
// 8B-lane / 128B-segment stores into vtB. Removes the transpose_v kernel
// and its 32 MB HBM round-trip.
__global__ __launch_bounds__(512, 2) void gemm256_qkv(const unsigned short* __restrict__ A,
                                                      const unsigned short* __restrict__ Bt,
                                                      const float* __restrict__ bias,
                                                      unsigned short* __restrict__ qB,
                                                      unsigned short* __restrict__ kB,
                                                      unsigned short* __restrict__ vtB) {
  constexpr int K = 1024;
  constexpr int NT = K / 64;            // 16 K-tiles
  __shared__ __align__(16) unsigned short As[32768];   // 64KB: [buf][half][128][64]
  __shared__ __align__(16) unsigned short Bs[32768];   // 64KB

  const int tid  = threadIdx.x;
  const int lane = tid & 63;
  const int wv   = tid >> 6;            // 0..7
  const int l15  = lane & 15, quad = lane >> 4;
  const int wr   = wv >> 1;             // 0..3  (32-row slice within each qm-half)
  const int wc   = wv & 1;              // 0..1  (64-col slice within each qn-half)

  // XCD-bijective swizzle: 384 blocks, 48 per XCD chunk
  const int w = (blockIdx.x & 7) * 48 + (blockIdx.x >> 3);
  const int tileM = (w & 31) * 256;     // 32 M-tiles
  const int tileN = (w >> 5) * 256;     // 12 N-tiles

  const int sr  = tid >> 3;
  const int scs = ((tid & 7) ^ (sr & 7)) * 8;
  const unsigned short* gA = A  + (size_t)(tileM + sr) * K + scs;
  const unsigned short* gB = Bt + (size_t)(tileN + sr) * K + scs;

  auto stageA = [&](int h, int ko, int wbuf) {
    const unsigned short* g = gA + (size_t)(h * 128) * K + ko;
    unsigned short* l = &As[wbuf * 16384 + h * 8192 + tid * 8];
    async_cp16(g, l);
    async_cp16(g + (size_t)64 * K, l + 4096);
  };
  auto stageB = [&](int h, int ko, int wbuf) {
    const unsigned short* g = gB + (size_t)(h * 128) * K + ko;
    unsigned short* l = &Bs[wbuf * 16384 + h * 8192 + tid * 8];
    async_cp16(g, l);
    async_cp16(g + (size_t)64 * K, l + 4096);
  };

  const int rA  = wr * 32 + l15;
  const int rB  = wc * 64 + l15;
  const int ck0 = ((0 + quad) ^ (l15 & 7)) * 8;
  const int ck1 = ((4 + quad) ^ (l15 & 7)) * 8;

  f32x4 acc[2][2][2][4] = {};                     // [qm][qn][fm][fn]

#define MFMA16(QM, QN, AF, BF)                                                          \
  do {                                                                                  \
    _Pragma("unroll") for (int fm = 0; fm < 2; ++fm)                                    \
    _Pragma("unroll") for (int fn = 0; fn < 4; ++fn) {                                  \
      acc[QM][QN][fm][fn] = mfma16(AF[fm][0], BF[fn][0], acc[QM][QN][fm][fn]);          \
      acc[QM][QN][fm][fn] = mfma16(AF[fm][1], BF[fn][1], acc[QM][QN][fm][fn]);          \
    }                                                                                   \
  } while (0)

  stageA(0, 0, 0);
  stageB(0, 0, 0);
  stageB(1, 0, 0);
  stageA(1, 0, 0);
  asm volatile("s_waitcnt vmcnt(4)" ::: "memory");
  asm volatile("s_barrier" ::: "memory");

  #pragma unroll 2
  for (int kt = 0; kt < NT; ++kt) {
    const int buf = kt & 1;
    const unsigned short* Ab = &As[buf * 16384];
    const unsigned short* Bb = &Bs[buf * 16384];
    const int wbuf = buf ^ 1;
    const bool st = (kt + 1) < NT;
    const int ko = (kt + 1) * 64;

    short8 a[2][2], b0[4][2], b1[4][2];

    // ---- phase 0: quadrant (0,0); reads A-half0 + B-half0
    #pragma unroll
    for (int fm = 0; fm < 2; ++fm) {
      a[fm][0] = *(const short8*)&Ab[(rA + fm * 16) * 64 + ck0];
      a[fm][1] = *(const short8*)&Ab[(rA + fm * 16) * 64 + ck1];
    }
    #pragma unroll
    for (int fn = 0; fn < 4; ++fn) {
      b0[fn][0] = *(const short8*)&Bb[(rB + fn * 16) * 64 + ck0];
      b0[fn][1] = *(const short8*)&Bb[(rB + fn * 16) * 64 + ck1];
    }
    if (st) stageA(0, ko, wbuf);
    asm volatile("s_waitcnt lgkmcnt(0)" ::: "memory");
    __builtin_amdgcn_sched_barrier(0);
    __builtin_amdgcn_s_setprio(1);
    MFMA16(0, 0, a, b0);
    __builtin_amdgcn_s_setprio(0);
    if (st) asm volatile("s_waitcnt vmcnt(4)" ::: "memory");   // force Bh1(kt)
    else    asm volatile("s_waitcnt vmcnt(2)" ::: "memory");
    asm volatile("s_barrier" ::: "memory");

    // ---- phase 1: quadrant (0,1); reads B-half1
    #pragma unroll
    for (int fn = 0; fn < 4; ++fn) {
      b1[fn][0] = *(const short8*)&Bb[8192 + (rB + fn * 16) * 64 + ck0];
      b1[fn][1] = *(const short8*)&Bb[8192 + (rB + fn * 16) * 64 + ck1];
    }
    if (st) stageB(0, ko, wbuf);
    asm volatile("s_waitcnt lgkmcnt(0)" ::: "memory");
    __builtin_amdgcn_sched_barrier(0);
    __builtin_amdgcn_s_setprio(1);
    MFMA16(0, 1, a, b1);
    __builtin_amdgcn_s_setprio(0);
    if (st) asm volatile("s_waitcnt vmcnt(4)" ::: "memory");   // force Ah1(kt)
    else    asm volatile("s_waitcnt vmcnt(0)" ::: "memory");
    asm volatile("s_barrier" ::: "memory");

    // ---- phase 2: quadrant (1,0); reads A-half1
    #pragma unroll
    for (int fm = 0; fm < 2; ++fm) {
      a[fm][0] = *(const short8*)&Ab[8192 + (rA + fm * 16) * 64 + ck0];
      a[fm][1] = *(const short8*)&Ab[8192 + (rA + fm * 16) * 64 + ck1];
    }
    if (st) stageB(1, ko, wbuf);
    asm volatile("s_waitcnt lgkmcnt(0)" ::: "memory");
    __builtin_amdgcn_sched_barrier(0);
    __builtin_amdgcn_s_setprio(1);
    MFMA16(1, 0, a, b0);
    __builtin_amdgcn_s_setprio(0);
    asm volatile("s_barrier" ::: "memory");

    // ---- phase 3: quadrant (1,1); no ds_reads
    if (st) stageA(1, ko, wbuf);
    __builtin_amdgcn_s_setprio(1);
    MFMA16(1, 1, a, b1);
    __builtin_amdgcn_s_setprio(0);
    if (st) asm volatile("s_waitcnt vmcnt(4)" ::: "memory");   // force Ah0+Bh0(kt+1)
    asm volatile("s_barrier" ::: "memory");
  }
#undef MFMA16

  if (tileN < 2048) {
    // ---- Q/K epilogue: per-wave LDS restage -> coalesced b128 stores
    unsigned short* E = &As[wv * 2304];   // 32 x 72, wave-local
    #pragma unroll
    for (int qm = 0; qm < 2; ++qm) {
      #pragma unroll
      for (int qn = 0; qn < 2; ++qn) {
        const int colBase = tileN + qn * 128 + wc * 64;
        const int rowBase = tileM + qm * 128 + wr * 32;
        #pragma unroll
        for (int fn = 0; fn < 4; ++fn) {
          const int col = colBase + fn * 16 + l15;
          const float bv = bias[col];
          const float sc = (col < 1024) ? 0.180336880f : 1.0f;  // Q: fold 0.125*log2e
          #pragma unroll
          for (int fm = 0; fm < 2; ++fm)
            #pragma unroll
            for (int r = 0; r < 4; ++r)
              E[(fm * 16 + quad * 4 + r) * 72 + fn * 16 + l15] =
                  f2b16((acc[qm][qn][fm][fn][r] + bv) * sc);
        }
        const int secq = colBase >> 10;                    // 0=Q, 1=K
        const int hh   = (colBase & 1023) >> 6;
        unsigned short* outSec = (secq == 0) ? qB : kB;
        #pragma unroll
        for (int it = 0; it < 4; ++it) {
          const int lrow = it * 8 + (lane >> 3);
          const int row = rowBase + lrow;
          const int b_ = row >> 11, tt = row & 2047;
          const u16x8 val = *(const u16x8*)&E[lrow * 72 + (lane & 7) * 8];
          *(u16x8*)(outSec + ((size_t)(b_ * 16 + hh) * T_ + tt) * 64 + (lane & 7) * 8) = val;
        }
      }
    }
  } else {
    // ---- V epilogue: fused transpose -> vtB[bh][dv][t'] (c' permuted).
    // c'(u) = 32*(wr&1) + 8*quad + 4*fm + r  (inverse of attn's t(c) map).
    // Cross-wave tiles [64 dv][stride 68] in dead As/Bs; per qm pass:
    // wr<2 waves fill As tiles (tb even), wr>=2 fill Bs (tb odd); then each
    // wave stores one (tb, head) tile with 8B/lane, 128B-contiguous rows.
    const int b_    = tileM >> 11;
    const int tbase = tileM & 2047;
    const int h0    = (tileN - 2048) >> 6;    // global head offset of col 0
    unsigned short* TL = (wr < 2) ? As : Bs;  // write-side tile array
    const int cpr = 32 * (wr & 1) + 8 * quad; // c' row-independent part
    #pragma unroll
    for (int qm = 0; qm < 2; ++qm) {
      // write phase
      #pragma unroll
      for (int qn = 0; qn < 2; ++qn) {
        const int head = qn * 2 + wc;
        const int colBase = tileN + qn * 128 + wc * 64;
        #pragma unroll
        for (int fn = 0; fn < 4; ++fn) {
          const int dv = fn * 16 + l15;
          const float bv = bias[colBase + fn * 16 + l15];
          #pragma unroll
          for (int fm = 0; fm < 2; ++fm)
            #pragma unroll
            for (int r = 0; r < 4; ++r)
              TL[head * 4352 + dv * 68 + cpr + 4 * fm + r] =
                  f2b16(acc[qm][qn][fm][fn][r] + bv);
        }
      }
      __syncthreads();
      // store phase: wave wv -> tile (tb = qm*2 + (wv>>2), head = wv&3)
      {
        const unsigned short* SA = (wv < 4) ? As : Bs;
        const int head = wv & 3;
        const int tb   = qm * 2 + (wv >> 2);
        const size_t base = ((size_t)(b_ * 16 + h0 + head) * 64) * T_ + tbase + tb * 64;
        const int c4 = (lane & 15) * 4;
        #pragma unroll
        for (int i = 0; i < 16; ++i) {
          const int dv = i * 4 + (lane >> 4);
          const ushort4 val = *(const ushort4*)&SA[head * 4352 + dv * 68 + c4];
          *(ushort4*)(vtB + base + (size_t)dv * T_ + c4) = val;
        }
      }
      __syncthreads();
    }
  }
}

// ------ 128x256 8-phase GEMM (output projection, MODE 1 fp32+resid) -----
template <int MODE, int NN>
__global__ __launch_bounds__(512, 2) void gemm8p(const unsigned short* __restrict__ A,
                                                 const unsigned short* __restrict__ Bt,
                                                 const float* __restrict__ bias,
                                                 const float* __restrict__ resid,
                                                 float* __restrict__ outF) {
  constexpr int K = 1024;
  constexpr int NT = 16;
  __shared__ __align__(16) unsigned short As[16384];
  __shared__ __align__(16) unsigned short Bs[32768];

  const int tid  = threadIdx.x;
  const int lane = tid & 63;
  const int wv   = tid >> 6;
  const int l15  = lane & 15, quad = lane >> 4;
  const int wr   = wv >> 1;
  const int wc   = wv & 1;

  constexpr int CPX = (64 * (NN / 256)) / 8;
  const int w = (blockIdx.x & 7) * CPX + (blockIdx.x >> 3);
  const int tileM = (w & 63) * 128;
  const int tileN = (w >> 6) * 256;

  const int sr  = tid >> 3;
  const int scs = ((tid & 7) ^ (sr & 7)) * 8;
  const unsigned short* gA = A  + (size_t)(tileM + sr) * K + scs;
  const unsigned short* gB = Bt + (size_t)(tileN + sr) * K + scs;

  auto stA = [&](int h, int ko, int wb) {
    async_cp16(gA + (size_t)(h * 64) * K + ko, &As[wb * 8192 + h * 4096 + tid * 8]);
  };
  auto stB = [&](int h, int ko, int wb) {
    const unsigned short* g = gB + (size_t)(h * 128) * K + ko;
    unsigned short* l = &Bs[wb * 16384 + h * 8192 + tid * 8];
    async_cp16(g, l);
    async_cp16(g + (size_t)64 * K, l + 4096);
  };

  const int rA  = wr * 16 + l15;
  const int rB  = wc * 64 + l15;
  const int ck0 = ((0 + quad) ^ (l15 & 7)) * 8;
  const int ck1 = ((4 + quad) ^ (l15 & 7)) * 8;

  f32x4 acc[2][2][4] = {};

  stA(0, 0, 0); stB(0, 0, 0); stB(1, 0, 0); stA(1, 0, 0);
  asm volatile("s_waitcnt vmcnt(3)" ::: "memory");
  asm volatile("s_barrier" ::: "memory");

  #pragma unroll 2
  for (int kt = 0; kt < NT; ++kt) {
    const int buf = kt & 1;
    const unsigned short* Ab = &As[buf * 8192];
    const unsigned short* Bb = &Bs[buf * 16384];
    const int wb = buf ^ 1;
    const bool st = (kt + 1) < NT;
    const int ko = (kt + 1) * 64;

    short8 a[2], b0[4][2], b1[4][2];

    a[0] = *(const short8*)&Ab[rA * 64 + ck0];
    a[1] = *(const short8*)&Ab[rA * 64 + ck1];
    #pragma unroll
    for (int fn = 0; fn < 4; ++fn) {
      b0[fn][0] = *(const short8*)&Bb[(rB + fn * 16) * 64 + ck0];
      b0[fn][1] = *(const short8*)&Bb[(rB + fn * 16) * 64 + ck1];
    }
    if (st) stA(0, ko, wb);
    asm volatile("s_waitcnt lgkmcnt(0)" ::: "memory");
    __builtin_amdgcn_sched_barrier(0);
    __builtin_amdgcn_s_setprio(1);
    #pragma unroll
    for (int fn = 0; fn < 4; ++fn) {
      acc[0][0][fn] = mfma16(a[0], b0[fn][0], acc[0][0][fn]);
      acc[0][0][fn] = mfma16(a[1], b0[fn][1], acc[0][0][fn]);
    }
    __builtin_amdgcn_s_setprio(0);
    if (st) asm volatile("s_waitcnt vmcnt(2)" ::: "memory");
    else    asm volatile("s_waitcnt vmcnt(1)" ::: "memory");
    asm volatile("s_barrier" ::: "memory");

    #pragma unroll
    for (int fn = 0; fn < 4; ++fn) {
      b1[fn][0] = *(const short8*)&Bb[8192 + (rB + fn * 16) * 64 + ck0];
      b1[fn][1] = *(const short8*)&Bb[8192 + (rB + fn * 16) * 64 + ck1];
    }
    if (st) stB(0, ko, wb);
    asm volatile("s_waitcnt lgkmcnt(0)" ::: "memory");
    __builtin_amdgcn_sched_barrier(0);
    __builtin_amdgcn_s_setprio(1);
    #pragma unroll
    for (int fn = 0; fn < 4; ++fn) {
      acc[0][1][fn] = mfma16(a[0], b1[fn][0], acc[0][1][fn]);
      acc[0][1][fn] = mfma16(a[1], b1[fn][1], acc[0][1][fn]);
    }
    __builtin_amdgcn_s_setprio(0);
    if (st) asm volatile("s_waitcnt vmcnt(3)" ::: "memory");
    else    asm volatile("s_waitcnt vmcnt(0)" ::: "memory");
    asm volatile("s_barrier" ::: "memory");

    a[0] = *(const short8*)&Ab[4096 + rA * 64 + ck0];
    a[1] = *(const short8*)&Ab[4096 + rA * 64 + ck1];
    if (st) stB(1, ko, wb);
    asm volatile("s_waitcnt lgkmcnt(0)" ::: "memory");
    __builtin_amdgcn_sched_barrier(0);
    __builtin_amdgcn_s_setprio(1);
    #pragma unroll
    for (int fn = 0; fn < 4; ++fn) {
      acc[1][0][fn] = mfma16(a[0], b0[fn][0], acc[1][0][fn]);
      acc[1][0][fn] = mfma16(a[1], b0[fn][1], acc[1][0][fn]);
    }
    __builtin_amdgcn_s_setprio(0);
    asm volatile("s_barrier" ::: "memory");

    if (st) stA(1, ko, wb);
    __builtin_amdgcn_s_setprio(1);
    #pragma unroll
    for (int fn = 0; fn < 4; ++fn) {
      acc[1][1][fn] = mfma16(a[0], b1[fn][0], acc[1][1][fn]);
      acc[1][1][fn] = mfma16(a[1], b1[fn][1], acc[1][1][fn]);
    }
    __builtin_amdgcn_s_setprio(0);
    if (st) asm volatile("s_waitcnt vmcnt(3)" ::: "memory");
    asm volatile("s_barrier" ::: "memory");
  }

  #pragma unroll
  for (int qm = 0; qm < 2; ++qm) {
    #pragma unroll
    for (int qn = 0; qn < 2; ++qn) {
      #pragma unroll
      for (int fn = 0; fn < 4; ++fn) {
        const int col = tileN + qn * 128 + wc * 64 + fn * 16 + l15;
        const float bv = bias[col];
        #pragma unroll
        for (int r = 0; r < 4; ++r) {
          const int row = tileM + qm * 64 + wr * 16 + quad * 4 + r;
          const size_t idx = (size_t)row * NN + col;
          outF[idx] = acc[qm][qn][fn][r] + bv + resid[idx];
        }
      }
    }
  }
}

// ---------------- MFMA flash attention v8 (unchanged) -------------------
__global__ __launch_bounds__(256, 4) void attn_mfma(const unsigned short* __restrict__ qB,
                                                    const unsigned short* __restrict__ kB,
                                                    const unsigned short* __restrict__ vtB,
                                                    unsigned short* __restrict__ aout) {
  __shared__ unsigned short Ks[2][64 * 64];
  __shared__ unsigned short Vs[2][64 * 64];

  const int tid = threadIdx.x;
  const int bid = blockIdx.x;
  const int bh = bid & 63;
  const int qb = bid >> 6;
  const int b = bh >> 4, h = bh & 15;
  const int wv = tid >> 6, lane = tid & 63;
  const int l15 = lane & 15, quad = lane >> 4;

  const unsigned short* qP = qB  + (size_t)bh * T_ * 64;
  const unsigned short* kP = kB  + (size_t)bh * T_ * 64;
  const unsigned short* vP = vtB + (size_t)bh * 64 * T_;
  const int q0 = qb * 128 + wv * 32;

  short8 qf[2][2];
  #pragma unroll
  for (int mi = 0; mi < 2; ++mi)
    #pragma unroll
    for (int ks = 0; ks < 2; ++ks)
      qf[mi][ks] = *(const short8*)(qP + ((size_t)(q0 + mi * 16 + l15)) * 64 + ks * 32 + quad * 8);

  const short8 onesf = {0x3F80, 0x3F80, 0x3F80, 0x3F80, 0x3F80, 0x3F80, 0x3F80, 0x3F80};
  f32x4 accO[2][5] = {};

  const int lrow  = lane >> 3;
  const int lchnk = (lane & 7) ^ (lrow & 7);
  const size_t kOff0 = (size_t)((wv * 2 + 0) * 8 + lrow) * 64 + lchnk * 8;
  const size_t kOff1 = (size_t)((wv * 2 + 1) * 8 + lrow) * 64 + lchnk * 8;
  const size_t vOff0 = (size_t)((wv * 2 + 0) * 8 + lrow) * T_ + lchnk * 8;
  const size_t vOff1 = (size_t)((wv * 2 + 1) * 8 + lrow) * T_ + lchnk * 8;
  const int lOff0 = (wv * 2 + 0) * 512 + lane * 8;
  const int lOff1 = (wv * 2 + 1) * 512 + lane * 8;

  async_cp16(kP + kOff0, &Ks[0][lOff0]);
  async_cp16(kP + kOff1, &Ks[0][lOff1]);
  async_cp16(vP + vOff0, &Vs[0][lOff0]);
  async_cp16(vP + vOff1, &Vs[0][lOff1]);
  __syncthreads();

  for (int kt = 0; kt < 32; ++kt) {
    const int buf = kt & 1;
    if (kt + 1 < 32) {
      const unsigned short* kg = kP + (size_t)(kt + 1) * 64 * 64;
      const unsigned short* vg = vP + (kt + 1) * 64;
      async_cp16(kg + kOff0, &Ks[buf ^ 1][lOff0]);
      async_cp16(kg + kOff1, &Ks[buf ^ 1][lOff1]);
      async_cp16(vg + vOff0, &Vs[buf ^ 1][lOff0]);
      async_cp16(vg + vOff1, &Vs[buf ^ 1][lOff1]);
    }
    const unsigned short* K_ = Ks[buf];
    const unsigned short* V_ = Vs[buf];

    f32x4 accT[4][2] = {};
    #pragma unroll
    for (int ks = 0; ks < 2; ++ks) {
      #pragma unroll
      for (int cc = 0; cc < 4; ++cc) {
        const short8 kb = *(const short8*)&K_[(cc * 16 + l15) * 64 +
                                              (((ks << 2) | quad) ^ (l15 & 7)) * 8];
        accT[cc][0] = mfma16(kb, qf[0][ks], accT[cc][0]);
        accT[cc][1] = mfma16(kb, qf[1][ks], accT[cc][1]);
      }
    }

    short8 pa[2][2];
    #pragma unroll
    for (int mi = 0; mi < 2; ++mi) {
      #pragma unroll
      for (int ks = 0; ks < 2; ++ks) {
        union { unsigned short u[8]; short8 s; } pk;
        #pragma unroll
        for (int r = 0; r < 4; ++r) {
          union { float f; unsigned int u; } e0, e1;
          e0.f = __builtin_amdgcn_exp2f(accT[2 * ks + 0][mi][r]);
          e1.f = __builtin_amdgcn_exp2f(accT[2 * ks + 1][mi][r]);
          pk.u[r]     = (unsigned short)(e0.u >> 16);
          pk.u[4 + r] = (unsigned short)(e1.u >> 16);
        }
        pa[mi][ks] = pk.s;
      }
    }

    #pragma unroll
    for (int ks = 0; ks < 2; ++ks) {
      short8 vb[4];
      #pragma unroll
      for (int nj = 0; nj < 4; ++nj)
        vb[nj] = *(const short8*)&V_[(nj * 16 + l15) * 64 +
                                     (((ks << 2) | quad) ^ (l15 & 7)) * 8];
      #pragma unroll
      for (int mi = 0; mi < 2; ++mi) {
        #pragma unroll
        for (int nj = 0; nj < 4; ++nj)
          accO[mi][nj] = mfma16(pa[mi][ks], vb[nj], accO[mi][nj]);
        accO[mi][4] = mfma16(pa[mi][ks], onesf, accO[mi][4]);
      }
    }

    __syncthreads();
  }

  #pragma unroll
  for (int mi = 0; mi < 2; ++mi) {
    #pragma unroll
    for (int r = 0; r < 4; ++r) {
      const float inv = 1.0f / accO[mi][4][r];
      const int row = q0 + mi * 16 + quad * 4 + r;
      unsigned short* op = aout + (size_t)(b * T_ + row) * D_ + h * 64 + l15;
      #pragma unroll
      for (int nj = 0; nj < 4; ++nj)
        op[nj * 16] = f2b16(accO[mi][nj][r] * inv);
    }
  }
}

extern "C" void kernel_launch(void* const* d_in, const int* in_sizes, int n_in,
                              void* d_out, int out_size, void* d_ws, size_t ws_size,
                              hipStream_t stream) {
  const float* x      = (const float*)d_in[0];
  const float* w_qkv  = (const float*)d_in[1];
  const float* b_qkv  = (const float*)d_in[2];
  const float* w_proj = (const float*)d_in[3];
  const float* b_proj = (const float*)d_in[4];
  const float* ln_g   = (const float*)d_in[5];
  const float* ln_b   = (const float*)d_in[6];
  float* out = (float*)d_out;

  char* ws = (char*)d_ws;
  unsigned short* xn   = (unsigned short*)(ws);                       // 16 MB (reused as aout)
  unsigned short* wTq  = (unsigned short*)(ws + (size_t)(16 << 20));  //  6 MB
  unsigned short* wTp  = (unsigned short*)(ws + (size_t)(22 << 20));  //  2 MB
  unsigned short* qBuf = (unsigned short*)(ws + (size_t)(24 << 20));  // 16 MB
  unsigned short* kBuf = (unsigned short*)(ws + (size_t)(40 << 20));  // 16 MB
  unsigned short* vtB  = (unsigned short*)(ws + (size_t)(72 << 20));  // 16 MB
  unsigned short* aout = xn;   // xn is dead after QKV gemm; attn reuses it

  // 1. fused prep: LN + both weight transposes (one dispatch)
  prep_kernel<<<12288, 256, 0, stream>>>(x, ln_g, ln_b, xn, w_qkv, wTq, w_proj, wTp);
  // 2. QKV projection (256^2 8-phase) with fused V-transpose epilogue
  gemm256_qkv<<<384, 512, 0, stream>>>(xn, wTq, b_qkv, qBuf, kBuf, vtB);
  // 3. MFMA flash attention v8
  attn_mfma<<<1024, 256, 0, stream>>>(qBuf, kBuf, vtB, aout);
  // 4. output projection + bias + residual, fp32 out
  gemm8p<1, 1024><<<256, 512, 0, stream>>>(aout, wTp, b_proj, x, out);
}